// Round 11
// baseline (233.187 us; speedup 1.0000x reference)
//
#include <hip/hip_runtime.h>

typedef unsigned short u16;
typedef unsigned int u32;
typedef __bf16 bf16x8 __attribute__((ext_vector_type(8)));
typedef float f32x4 __attribute__((ext_vector_type(4)));
typedef float f32x16 __attribute__((ext_vector_type(16)));

#define D_EMB 1024
#define T_SEQ 2048
#define NH 16
#define HD 64

#define GLB(p) ((const __attribute__((address_space(1))) unsigned int*)(p))
#define LDSP(p) ((__attribute__((address_space(3))) unsigned int*)(p))
#define VMCNT(n) asm volatile("s_waitcnt vmcnt(" #n ")" ::: "memory")
#define LGKM0() asm volatile("s_waitcnt lgkmcnt(0)" ::: "memory")

__device__ __forceinline__ u16 f2bf(float f) {
  union { float f; unsigned u; } c; c.f = f;
  unsigned u = c.u;
  unsigned r = (u + 0x7FFFu + ((u >> 16) & 1u)) >> 16;
  return (u16)r;
}
__device__ __forceinline__ u32 fbits(float f) {
  union { float f; unsigned u; } c; c.f = f; return c.u;
}

// ---------------- fused prep (R0-R6 proven 32x32 version) ----------------
__global__ __launch_bounds__(256) void prep_kernel(
    const float* __restrict__ x, const float* __restrict__ e,
    const float* __restrict__ W_q, const float* __restrict__ W_en, const float* __restrict__ W_o,
    u16* __restrict__ xb, u16* __restrict__ eb,
    u16* __restrict__ Wqt, u16* __restrict__ Went, u16* __restrict__ Wot) {
  __shared__ float tile[32][33];
  const int bid = blockIdx.x, tid = threadIdx.x;
  if (bid < 8192) {
    const float* in = (bid < 4096) ? x : e;
    u16* out = (bid < 4096) ? xb : eb;
    int i = (bid & 4095) * 256 + tid;
    float4 v = reinterpret_cast<const float4*>(in)[i];
    ushort4 o;
    o.x = f2bf(v.x); o.y = f2bf(v.y); o.z = f2bf(v.z); o.w = f2bf(v.w);
    reinterpret_cast<ushort4*>(out)[i] = o;
    return;
  }
  const float* in; u16* out; int K, N, bx, by;
  int rem = bid - 8192;
  if (rem < 1024)      { in = W_q;  out = Wqt;  K = 1024; N = 1024; bx = rem & 31; by = rem >> 5; }
  else if (rem < 3072) { int r2 = rem - 1024; in = W_en; out = Went; K = 1024; N = 2048; bx = r2 & 63; by = r2 >> 6; }
  else                 { int r3 = rem - 3072; in = W_o;  out = Wot;  K = 1024; N = 1024; bx = r3 & 31; by = r3 >> 5; }
  int tx = tid & 31, ty = tid >> 5;
  int n0 = bx * 32, k0 = by * 32;
#pragma unroll
  for (int s = 0; s < 4; s++)
    tile[ty + 8 * s][tx] = in[(size_t)(k0 + ty + 8 * s) * N + n0 + tx];
  __syncthreads();
#pragma unroll
  for (int s = 0; s < 4; s++)
    out[(size_t)(n0 + ty + 8 * s) * K + k0 + tx] = f2bf(tile[tx][ty + 8 * s]);
}

// ---------------- fused QKV projection GEMM: 128x128, BK=32, A-direct-to-registers ----------
// Diagnosis (R10 post-mortem): phase wall 1175 cyc == 96 KB/CU/phase LDS reads at 85 B/cyc —
// LDS-read-throughput bound. Fix: A fragments are 16B k-contiguous = native global layout,
// so load them global->VGPR directly (double-buffered sets, issued one phase ahead; the
// __syncthreads vmcnt drain then costs nothing). B keeps the proven LDS path.
// LDS reads/phase halve: 96 KB -> 48 KB per CU.
__global__ __launch_bounds__(256) void proj_kernel(
    const u16* __restrict__ xb, const u16* __restrict__ eb,
    const u16* __restrict__ Wqt, const u16* __restrict__ Went,
    u16* __restrict__ qw, u16* __restrict__ kw, u16* __restrict__ vTw) {
  __shared__ u16 Bl0[128 * 32], Bl1[128 * 32];   // 16 KB
  const int tid = threadIdx.x;
  const int nb = blockIdx.x, mb = blockIdx.y;
  const int wave = tid >> 6, lane = tid & 63;
  const int ln15 = lane & 15, quad = lane >> 4;
  const int wm = wave & 1, wn = wave >> 1;

  const u16* A = (nb < 8) ? xb : eb;
  const u16* Wt = (nb < 8) ? (Wqt + (size_t)nb * 128 * D_EMB)
                           : (Went + ((size_t)nb * 128 - D_EMB) * D_EMB);

  // B staging addresses (global_load_lds), same as R3
  const int srow = lane >> 2, sch = lane & 3;
  const int gch = sch ^ ((srow >> 1) & 3);
  const u16* gB = Wt + (size_t)(wave * 32 + srow) * D_EMB + gch * 8;

  // A fragment pointers: row = mb*128 + wm*64 + mt*16 + ln15, k-chunk = quad*8
  const u16* aP[4];
#pragma unroll
  for (int mt = 0; mt < 4; mt++)
    aP[mt] = A + (size_t)(mb * 128 + wm * 64 + mt * 16 + ln15) * D_EMB + quad * 8;

  auto stageB = [&](int kb, u16* BL) {
    char* lB = (char*)BL + wave * 2048;
#pragma unroll
    for (int it = 0; it < 2; it++)
      __builtin_amdgcn_global_load_lds(GLB(gB + (size_t)it * 16 * D_EMB + kb), LDSP(lB + it * 1024), 16, 0, 0);
  };

  f32x4 acc[4][4] = {};
  bf16x8 aS0[4], aS1[4];

  auto issueA0 = [&](int kb) {
#pragma unroll
    for (int mt = 0; mt < 4; mt++)
      aS0[mt] = *reinterpret_cast<const bf16x8*>(aP[mt] + kb);
  };
  auto issueA1 = [&](int kb) {
#pragma unroll
    for (int mt = 0; mt < 4; mt++)
      aS1[mt] = *reinterpret_cast<const bf16x8*>(aP[mt] + kb);
  };

  auto compute = [&](const bf16x8* aS, const u16* BL) {
    bf16x8 bfr[4];
#pragma unroll
    for (int nt = 0; nt < 4; nt++) {
      int r = wn * 64 + nt * 16 + ln15;
      bfr[nt] = *reinterpret_cast<const bf16x8*>(&BL[r * 32 + ((quad ^ ((r >> 1) & 3)) * 8)]);
    }
#pragma unroll
    for (int mt = 0; mt < 4; mt++)
#pragma unroll
      for (int nt = 0; nt < 4; nt++)
        acc[mt][nt] = __builtin_amdgcn_mfma_f32_16x16x32_bf16(aS[mt], bfr[nt], acc[mt][nt], 0, 0, 0);
  };

  issueA0(0);
  stageB(0, Bl0);
  for (int kb = 0; kb < D_EMB; kb += 64) {
    __syncthreads();
    issueA1(kb + 32);
    stageB(kb + 32, Bl1);
    compute(aS0, Bl0);
    __syncthreads();
    if (kb + 64 < D_EMB) {
      issueA0(kb + 64);
      stageB(kb + 64, Bl0);
    }
    compute(aS1, Bl1);
  }

  const float QSCL = 0.125f * 1.44269504f;
#pragma unroll
  for (int mt = 0; mt < 4; mt++) {
#pragma unroll
    for (int nt = 0; nt < 4; nt++) {
#pragma unroll
      for (int i = 0; i < 4; i++) {
        int rr = mb * 128 + wm * 64 + mt * 16 + quad * 4 + i;
        int c  = nb * 128 + wn * 64 + nt * 16 + ln15;
        float v = acc[mt][nt][i];
        int b = rr >> 11, t = rr & 2047;
        if (c < D_EMB) {
          int h = c >> 6, d = c & 63;
          qw[(((size_t)(b * NH + h)) * T_SEQ + t) * HD + d] = f2bf(v * QSCL);
        } else if (c < 2 * D_EMB) {
          int cc = c - D_EMB; int h = cc >> 6, d = cc & 63;
          kw[(((size_t)(b * NH + h)) * T_SEQ + t) * HD + d] = f2bf(v);
        } else {
          int cc = c - 2 * D_EMB; int h = cc >> 6, d = cc & 63;
          vTw[(((size_t)(b * NH + h)) * HD + d) * T_SEQ + t] = f2bf(v);
        }
      }
    }
  }
}

// ---------------- flash attention: R6-exact (lane-local P, depth-3, XCD head grouping) ------
__global__ __launch_bounds__(256) void attn_kernel(
    const u16* __restrict__ q, const u16* __restrict__ k,
    const u16* __restrict__ vT, u16* __restrict__ y) {
  __shared__ u16 Kl[3][64][64], Vl[3][64][64];   // 48 KB

  const int bid0 = blockIdx.x;                     // 512 blocks, 512%8==0
  const int wgid = (bid0 & 7) * 64 + (bid0 >> 3);  // bijective XCD chunking
  const int bh = wgid >> 4;                        // 4 heads per XCD chunk
  const int qt = wgid & 15;
  const int tid = threadIdx.x;
  const int wave = tid >> 6, lane = tid & 63;
  const int q32 = lane & 31, hi = lane >> 5;
  const int b = bh >> 4, h = bh & 15;

  // pi(q32): swap bit2 <-> bit3 (makes P lane-local; see R3 derivation)
  const int pq = (q32 & 19) | ((q32 & 8) >> 1) | ((q32 & 4) << 1);
  const int pq7 = pq & 7;

  const int qrow = qt * 128 + wave * 32 + q32;
  const u16* qbase = q + ((size_t)bh * T_SEQ + qrow) * HD;
  bf16x8 qf[4];
#pragma unroll
  for (int s = 0; s < 4; s++)
    qf[s] = *reinterpret_cast<const bf16x8*>(qbase + s * 16 + hi * 8);

  f32x16 o2[2] = {};
  float lp = 0.f;

  const int srow = (lane >> 3) & 7;
  const int gch  = (lane & 7) ^ srow;
  const u16* kg0 = k  + ((size_t)bh * T_SEQ + wave * 16 + srow) * HD + gch * 8;
  const u16* vg0 = vT + ((size_t)bh * HD + wave * 16 + srow) * T_SEQ + gch * 8;

  auto issue_dma = [&](int t, u16 (*KL)[64], u16 (*VL)[64]) {
    char* klb = (char*)KL + wave * 2048;
    char* vlb = (char*)VL + wave * 2048;
    const u16* kp = kg0 + (size_t)t * 64 * HD;
    const u16* vp = vg0 + t * 64;
    __builtin_amdgcn_global_load_lds(GLB(kp),             LDSP(klb),        16, 0, 0);
    __builtin_amdgcn_global_load_lds(GLB(kp + 8 * HD),    LDSP(klb + 1024), 16, 0, 0);
    __builtin_amdgcn_global_load_lds(GLB(vp),             LDSP(vlb),        16, 0, 0);
    __builtin_amdgcn_global_load_lds(GLB(vp + 8 * T_SEQ), LDSP(vlb + 1024), 16, 0, 0);
  };

  auto body = [&](const u16 (*KL)[64], const u16 (*VL)[64]) {
    f32x16 s2[2] = {};
    __builtin_amdgcn_s_setprio(1);
#pragma unroll
    for (int s = 0; s < 4; s++)
#pragma unroll
      for (int kt2 = 0; kt2 < 2; kt2++) {
        int r = kt2 * 32 + pq;
        bf16x8 kf = *reinterpret_cast<const bf16x8*>(&KL[r][(((s * 2 + hi) ^ pq7) * 8)]);
        s2[kt2] = __builtin_amdgcn_mfma_f32_32x32x16_bf16(kf, qf[s], s2[kt2], 0, 0, 0);
      }

#pragma unroll
    for (int s = 0; s < 4; s++) {
      const int kt2 = s >> 1;
      const int g0 = (2 * s) & 3;
      float e0 = __builtin_amdgcn_exp2f(s2[kt2][4 * g0 + 0]);
      float e1 = __builtin_amdgcn_exp2f(s2[kt2][4 * g0 + 1]);
      float e2 = __builtin_amdgcn_exp2f(s2[kt2][4 * g0 + 2]);
      float e3 = __builtin_amdgcn_exp2f(s2[kt2][4 * g0 + 3]);
      float e4 = __builtin_amdgcn_exp2f(s2[kt2][4 * g0 + 4]);
      float e5 = __builtin_amdgcn_exp2f(s2[kt2][4 * g0 + 5]);
      float e6 = __builtin_amdgcn_exp2f(s2[kt2][4 * g0 + 6]);
      float e7 = __builtin_amdgcn_exp2f(s2[kt2][4 * g0 + 7]);
      lp += ((e0 + e1) + (e2 + e3)) + ((e4 + e5) + (e6 + e7));
      u32 w0 = __builtin_amdgcn_perm(fbits(e1), fbits(e0), 0x07060302u);
      u32 w1 = __builtin_amdgcn_perm(fbits(e3), fbits(e2), 0x07060302u);
      u32 w2 = __builtin_amdgcn_perm(fbits(e5), fbits(e4), 0x07060302u);
      u32 w3 = __builtin_amdgcn_perm(fbits(e7), fbits(e6), 0x07060302u);
      union { u32 w[4]; bf16x8 v; } pu;
      pu.w[0] = w0; pu.w[1] = w1; pu.w[2] = w2; pu.w[3] = w3;
      bf16x8 pf = pu.v;
#pragma unroll
      for (int dt = 0; dt < 2; dt++) {
        int r = dt * 32 + q32;
        bf16x8 vf = *reinterpret_cast<const bf16x8*>(&VL[r][(((s * 2 + hi) ^ (r & 7)) * 8)]);
        o2[dt] = __builtin_amdgcn_mfma_f32_32x32x16_bf16(vf, pf, o2[dt], 0, 0, 0);
      }
    }
    __builtin_amdgcn_s_setprio(0);
  };

  issue_dma(0, Kl[0], Vl[0]);
  issue_dma(1, Kl[1], Vl[1]);
  issue_dma(2, Kl[2], Vl[2]);
  u16 (*cK)[64] = Kl[0]; u16 (*cV)[64] = Vl[0];
  u16 (*nK)[64] = Kl[1]; u16 (*nV)[64] = Vl[1];
  u16 (*mK)[64] = Kl[2]; u16 (*mV)[64] = Vl[2];

  for (int t = 0; t < 29; t++) {     // re-stage t+3 (max 31)
    VMCNT(8);
    __builtin_amdgcn_s_barrier();
    body(cK, cV);
    LGKM0();
    __builtin_amdgcn_s_barrier();
    issue_dma(t + 3, cK, cV);
    u16 (*tp)[64];
    tp = cK; cK = nK; nK = mK; mK = tp;
    tp = cV; cV = nV; nV = mV; mV = tp;
  }
  VMCNT(8); __builtin_amdgcn_s_barrier(); body(cK, cV);   // t=29
  VMCNT(4); __builtin_amdgcn_s_barrier(); body(nK, nV);   // t=30
  VMCNT(0); __builtin_amdgcn_s_barrier(); body(mK, mV);   // t=31

  lp += __shfl_xor(lp, 32, 64);
  const float inv = 1.0f / lp;

  const size_t ybase = ((size_t)b * T_SEQ + qrow) * D_EMB + h * 64;
#pragma unroll
  for (int dt = 0; dt < 2; dt++)
#pragma unroll
    for (int g = 0; g < 4; g++) {
      u16 b0 = f2bf(o2[dt][4 * g + 0] * inv), b1 = f2bf(o2[dt][4 * g + 1] * inv);
      u16 b2 = f2bf(o2[dt][4 * g + 2] * inv), b3 = f2bf(o2[dt][4 * g + 3] * inv);
      u32 dw0 = (u32)b0 | ((u32)b1 << 16);
      u32 dw1 = (u32)b2 | ((u32)b3 << 16);
      *reinterpret_cast<uint2*>(&y[ybase + dt * 32 + 8 * g + 4 * hi]) = make_uint2(dw0, dw1);
    }
}

// ---------------- output projection: R6-exact (64x128, BK=32, depth-3, XCD swizzle) ---------
__global__ __launch_bounds__(256) void oproj_kernel(
    const u16* __restrict__ yw, const u16* __restrict__ Wot, float* __restrict__ out) {
  __shared__ u16 Al[3][64 * 32], Bl[3][128 * 32];
  const int tid = threadIdx.x;
  const int bid0 = blockIdx.y * 8 + blockIdx.x;          // 512 blocks
  const int wgid = (bid0 & 7) * 64 + (bid0 >> 3);
  const int nb = wgid & 7, mb = wgid >> 3;
  const int wave = tid >> 6, lane = tid & 63;
  const int ln15 = lane & 15, quad = lane >> 4;
  const int wm = wave & 1, wn = wave >> 1;

  const int srow = lane >> 2, sch = lane & 3;
  const int gch = sch ^ ((srow >> 1) & 3);
  const u16* gA = yw  + (size_t)(mb * 64 + wave * 16 + srow) * D_EMB + gch * 8;
  const u16* gB = Wot + (size_t)(nb * 128 + wave * 32 + srow) * D_EMB + gch * 8;

  auto stage = [&](int kb, u16* AL, u16* BL) {
    char* lA = (char*)AL + wave * 1024;
    char* lB = (char*)BL + wave * 2048;
    __builtin_amdgcn_global_load_lds(GLB(gA + kb), LDSP(lA), 16, 0, 0);
#pragma unroll
    for (int it = 0; it < 2; it++)
      __builtin_amdgcn_global_load_lds(GLB(gB + (size_t)it * 16 * D_EMB + kb), LDSP(lB + it * 1024), 16, 0, 0);
  };

  f32x4 acc[2][4] = {};
  bf16x8 af[2], bfr[4];

  auto ldfrag = [&](const u16* AL, const u16* BL) {
#pragma unroll
    for (int mt = 0; mt < 2; mt++) {
      int r = wm * 32 + mt * 16 + ln15;
      af[mt] = *reinterpret_cast<const bf16x8*>(&AL[r * 32 + ((quad ^ ((r >> 1) & 3)) * 8)]);
    }
#pragma unroll
    for (int nt = 0; nt < 4; nt++) {
      int r = wn * 64 + nt * 16 + ln15;
      bfr[nt] = *reinterpret_cast<const bf16x8*>(&BL[r * 32 + ((quad ^ ((r >> 1) & 3)) * 8)]);
    }
  };
  auto domfma = [&]() {
    __builtin_amdgcn_s_setprio(1);
#pragma unroll
    for (int mt = 0; mt < 2; mt++)
#pragma unroll
      for (int nt = 0; nt < 4; nt++)
        acc[mt][nt] = __builtin_amdgcn_mfma_f32_16x16x32_bf16(af[mt], bfr[nt], acc[mt][nt], 0, 0, 0);
    __builtin_amdgcn_s_setprio(0);
  };

  stage(0,  Al[0], Bl[0]);
  stage(32, Al[1], Bl[1]);
  stage(64, Al[2], Bl[2]);
  u16 *cA = Al[0], *cB = Bl[0], *nA = Al[1], *nB = Bl[1], *mA = Al[2], *mB = Bl[2];

  for (int kb = 0; kb < 928; kb += 32) {
    VMCNT(6);
    __builtin_amdgcn_s_barrier();
    ldfrag(cA, cB);
    LGKM0();
    __builtin_amdgcn_s_barrier();
    stage(kb + 96, cA, cB);
    domfma();
    u16* t;
    t = cA; cA = nA; nA = mA; mA = t;
    t = cB; cB = nB; nB = mB; mB = t;
  }
  VMCNT(6); __builtin_amdgcn_s_barrier(); ldfrag(cA, cB); domfma();   // kb=928
  VMCNT(3); __builtin_amdgcn_s_barrier(); ldfrag(nA, nB); domfma();   // kb=960
  VMCNT(0); __builtin_amdgcn_s_barrier(); ldfrag(mA, mB); domfma();   // kb=992

#pragma unroll
  for (int mt = 0; mt < 2; mt++)
#pragma unroll
    for (int nt = 0; nt < 4; nt++)
#pragma unroll
      for (int i = 0; i < 4; i++) {
        int rr = mb * 64 + wm * 32 + mt * 16 + quad * 4 + i;
        int c  = nb * 128 + wn * 64 + nt * 16 + ln15;
        out[(size_t)rr * D_EMB + c] = acc[mt][nt][i];
      }
}

extern "C" void kernel_launch(void* const* d_in, const int* in_sizes, int n_in,
                              void* d_out, int out_size, void* d_ws, size_t ws_size,
                              hipStream_t stream) {
  const float* x    = (const float*)d_in[0];
  const float* e    = (const float*)d_in[1];
  const float* W_en = (const float*)d_in[2];
  const float* W_q  = (const float*)d_in[3];
  const float* W_o  = (const float*)d_in[4];
  float* out = (float*)d_out;

  char* w = (char*)d_ws;
  u16* xb   = (u16*)(w);
  u16* eb   = (u16*)(w + (8u  << 20));
  u16* Wqt  = (u16*)(w + (16u << 20));
  u16* Went = (u16*)(w + (18u << 20));
  u16* Wot  = (u16*)(w + (22u << 20));
  u16* qw   = (u16*)(w + (24u << 20));
  u16* kw   = (u16*)(w + (32u << 20));
  u16* vT   = (u16*)(w + (40u << 20));
  u16* yw   = (u16*)(w + (48u << 20));

  prep_kernel<<<12288, 256, 0, stream>>>(x, e, W_q, W_en, W_o, xb, eb, Wqt, Went, Wot);
  proj_kernel<<<dim3(24, 32), 256, 0, stream>>>(xb, eb, Wqt, Went, qw, kw, vT);
  attn_kernel<<<512, 256, 0, stream>>>(qw, kw, vT, yw);
  oproj_kernel<<<dim3(8, 64), 256, 0, stream>>>(yw, Wot, out);
}

// Round 12
// 188.775 us; speedup vs baseline: 1.2353x; 1.2353x over previous
//
#include <hip/hip_runtime.h>

typedef unsigned short u16;
typedef unsigned int u32;
typedef __bf16 bf16x8 __attribute__((ext_vector_type(8)));
typedef float f32x4 __attribute__((ext_vector_type(4)));
typedef float f32x16 __attribute__((ext_vector_type(16)));

#define D_EMB 1024
#define T_SEQ 2048
#define NH 16
#define HD 64

#define GLB(p) ((const __attribute__((address_space(1))) unsigned int*)(p))
#define LDSP(p) ((__attribute__((address_space(3))) unsigned int*)(p))
#define VMCNT(n) asm volatile("s_waitcnt vmcnt(" #n ")" ::: "memory")
#define LGKM0() asm volatile("s_waitcnt lgkmcnt(0)" ::: "memory")

__device__ __forceinline__ u16 f2bf(float f) {
  union { float f; unsigned u; } c; c.f = f;
  unsigned u = c.u;
  unsigned r = (u + 0x7FFFu + ((u >> 16) & 1u)) >> 16;
  return (u16)r;
}
__device__ __forceinline__ u32 fbits(float f) {
  union { float f; unsigned u; } c; c.f = f; return c.u;
}

// ---------------- fused prep ----------------
__global__ __launch_bounds__(256) void prep_kernel(
    const float* __restrict__ x, const float* __restrict__ e,
    const float* __restrict__ W_q, const float* __restrict__ W_en, const float* __restrict__ W_o,
    u16* __restrict__ xb, u16* __restrict__ eb,
    u16* __restrict__ Wqt, u16* __restrict__ Went, u16* __restrict__ Wot) {
  __shared__ float tile[32][33];
  const int bid = blockIdx.x, tid = threadIdx.x;
  if (bid < 8192) {
    const float* in = (bid < 4096) ? x : e;
    u16* out = (bid < 4096) ? xb : eb;
    int i = (bid & 4095) * 256 + tid;
    float4 v = reinterpret_cast<const float4*>(in)[i];
    ushort4 o;
    o.x = f2bf(v.x); o.y = f2bf(v.y); o.z = f2bf(v.z); o.w = f2bf(v.w);
    reinterpret_cast<ushort4*>(out)[i] = o;
    return;
  }
  const float* in; u16* out; int K, N, bx, by;
  int rem = bid - 8192;
  if (rem < 1024)      { in = W_q;  out = Wqt;  K = 1024; N = 1024; bx = rem & 31; by = rem >> 5; }
  else if (rem < 3072) { int r2 = rem - 1024; in = W_en; out = Went; K = 1024; N = 2048; bx = r2 & 63; by = r2 >> 6; }
  else                 { int r3 = rem - 3072; in = W_o;  out = Wot;  K = 1024; N = 1024; bx = r3 & 31; by = r3 >> 5; }
  int tx = tid & 31, ty = tid >> 5;
  int n0 = bx * 32, k0 = by * 32;
#pragma unroll
  for (int s = 0; s < 4; s++)
    tile[ty + 8 * s][tx] = in[(size_t)(k0 + ty + 8 * s) * N + n0 + tx];
  __syncthreads();
#pragma unroll
  for (int s = 0; s < 4; s++)
    out[(size_t)(n0 + ty + 8 * s) * K + k0 + tx] = f2bf(tile[tx][ty + 8 * s]);
}

// ---------------- fused QKV projection GEMM: 128x128, BK=32, depth-3 counted-vmcnt ----------
// + XCD swizzle: each XCD owns 4 contiguous mb-rows (R6-exact configuration).
__global__ __launch_bounds__(256) void proj_kernel(
    const u16* __restrict__ xb, const u16* __restrict__ eb,
    const u16* __restrict__ Wqt, const u16* __restrict__ Went,
    u16* __restrict__ qw, u16* __restrict__ kw, u16* __restrict__ vTw) {
  __shared__ u16 Al[3][128 * 32], Bl[3][128 * 32];   // 48 KB
  const int tid = threadIdx.x;
  const int bid0 = blockIdx.y * 24 + blockIdx.x;          // 768 blocks, 768%8==0
  const int wgid = (bid0 & 7) * 96 + (bid0 >> 3);         // bijective XCD chunking
  const int nb = wgid % 24, mb = wgid / 24;
  const int wave = tid >> 6, lane = tid & 63;
  const int ln15 = lane & 15, quad = lane >> 4;
  const int wm = wave & 1, wn = wave >> 1;

  const u16* A = (nb < 8) ? xb : eb;
  const u16* Wt = (nb < 8) ? (Wqt + (size_t)nb * 128 * D_EMB)
                           : (Went + ((size_t)nb * 128 - D_EMB) * D_EMB);

  const int srow = lane >> 2, sch = lane & 3;
  const int gch = sch ^ ((srow >> 1) & 3);
  const u16* gA = A + (size_t)(mb * 128 + wave * 32 + srow) * D_EMB + gch * 8;
  const u16* gB = Wt + (size_t)(wave * 32 + srow) * D_EMB + gch * 8;

  auto stage = [&](int kb, u16* AL, u16* BL) {
    char* lA = (char*)AL + wave * 2048;
    char* lB = (char*)BL + wave * 2048;
#pragma unroll
    for (int it = 0; it < 2; it++) {
      __builtin_amdgcn_global_load_lds(GLB(gA + (size_t)it * 16 * D_EMB + kb), LDSP(lA + it * 1024), 16, 0, 0);
      __builtin_amdgcn_global_load_lds(GLB(gB + (size_t)it * 16 * D_EMB + kb), LDSP(lB + it * 1024), 16, 0, 0);
    }
  };

  f32x4 acc[4][4] = {};
  bf16x8 af[4], bfr[4];

  auto ldfrag = [&](const u16* AL, const u16* BL) {
#pragma unroll
    for (int mt = 0; mt < 4; mt++) {
      int r = wm * 64 + mt * 16 + ln15;
      af[mt] = *reinterpret_cast<const bf16x8*>(&AL[r * 32 + ((quad ^ ((r >> 1) & 3)) * 8)]);
    }
#pragma unroll
    for (int nt = 0; nt < 4; nt++) {
      int r = wn * 64 + nt * 16 + ln15;
      bfr[nt] = *reinterpret_cast<const bf16x8*>(&BL[r * 32 + ((quad ^ ((r >> 1) & 3)) * 8)]);
    }
  };
  auto domfma = [&]() {
    __builtin_amdgcn_s_setprio(1);
#pragma unroll
    for (int mt = 0; mt < 4; mt++)
#pragma unroll
      for (int nt = 0; nt < 4; nt++)
        acc[mt][nt] = __builtin_amdgcn_mfma_f32_16x16x32_bf16(af[mt], bfr[nt], acc[mt][nt], 0, 0, 0);
    __builtin_amdgcn_s_setprio(0);
  };

  stage(0,  Al[0], Bl[0]);
  stage(32, Al[1], Bl[1]);
  stage(64, Al[2], Bl[2]);
  u16 *cA = Al[0], *cB = Bl[0], *nA = Al[1], *nB = Bl[1], *mA = Al[2], *mB = Bl[2];

  for (int kb = 0; kb < 928; kb += 32) {   // kb = 0..896, re-stage kb+96 (max 992)
    VMCNT(8);
    __builtin_amdgcn_s_barrier();
    ldfrag(cA, cB);
    LGKM0();
    __builtin_amdgcn_s_barrier();
    stage(kb + 96, cA, cB);
    domfma();
    u16* t;
    t = cA; cA = nA; nA = mA; mA = t;
    t = cB; cB = nB; nB = mB; mB = t;
  }
  VMCNT(8); __builtin_amdgcn_s_barrier(); ldfrag(cA, cB); domfma();   // kb=928
  VMCNT(4); __builtin_amdgcn_s_barrier(); ldfrag(nA, nB); domfma();   // kb=960
  VMCNT(0); __builtin_amdgcn_s_barrier(); ldfrag(mA, mB); domfma();   // kb=992

  const float QSCL = 0.125f * 1.44269504f;
#pragma unroll
  for (int mt = 0; mt < 4; mt++) {
#pragma unroll
    for (int nt = 0; nt < 4; nt++) {
#pragma unroll
      for (int i = 0; i < 4; i++) {
        int rr = mb * 128 + wm * 64 + mt * 16 + quad * 4 + i;
        int c  = nb * 128 + wn * 64 + nt * 16 + ln15;
        float v = acc[mt][nt][i];
        int b = rr >> 11, t = rr & 2047;
        if (c < D_EMB) {
          int h = c >> 6, d = c & 63;
          qw[(((size_t)(b * NH + h)) * T_SEQ + t) * HD + d] = f2bf(v * QSCL);
        } else if (c < 2 * D_EMB) {
          int cc = c - D_EMB; int h = cc >> 6, d = cc & 63;
          kw[(((size_t)(b * NH + h)) * T_SEQ + t) * HD + d] = f2bf(v);
        } else {
          int cc = c - 2 * D_EMB; int h = cc >> 6, d = cc & 63;
          vTw[(((size_t)(b * NH + h)) * HD + d) * T_SEQ + t] = f2bf(v);
        }
      }
    }
  }
}

// ---------------- flash attention: lane-local P, depth-3, XCD head grouping (R6-exact) ------
__global__ __launch_bounds__(256) void attn_kernel(
    const u16* __restrict__ q, const u16* __restrict__ k,
    const u16* __restrict__ vT, u16* __restrict__ y) {
  __shared__ u16 Kl[3][64][64], Vl[3][64][64];   // 48 KB

  const int bid0 = blockIdx.x;                     // 512 blocks, 512%8==0
  const int wgid = (bid0 & 7) * 64 + (bid0 >> 3);  // bijective XCD chunking
  const int bh = wgid >> 4;                        // 4 heads per XCD chunk
  const int qt = wgid & 15;
  const int tid = threadIdx.x;
  const int wave = tid >> 6, lane = tid & 63;
  const int q32 = lane & 31, hi = lane >> 5;
  const int b = bh >> 4, h = bh & 15;

  // pi(q32): swap bit2 <-> bit3 (makes P lane-local; see R3 derivation)
  const int pq = (q32 & 19) | ((q32 & 8) >> 1) | ((q32 & 4) << 1);
  const int pq7 = pq & 7;

  const int qrow = qt * 128 + wave * 32 + q32;
  const u16* qbase = q + ((size_t)bh * T_SEQ + qrow) * HD;
  bf16x8 qf[4];
#pragma unroll
  for (int s = 0; s < 4; s++)
    qf[s] = *reinterpret_cast<const bf16x8*>(qbase + s * 16 + hi * 8);

  f32x16 o2[2] = {};
  float lp = 0.f;

  const int srow = (lane >> 3) & 7;
  const int gch  = (lane & 7) ^ srow;
  const u16* kg0 = k  + ((size_t)bh * T_SEQ + wave * 16 + srow) * HD + gch * 8;
  const u16* vg0 = vT + ((size_t)bh * HD + wave * 16 + srow) * T_SEQ + gch * 8;

  auto issue_dma = [&](int t, u16 (*KL)[64], u16 (*VL)[64]) {
    char* klb = (char*)KL + wave * 2048;
    char* vlb = (char*)VL + wave * 2048;
    const u16* kp = kg0 + (size_t)t * 64 * HD;
    const u16* vp = vg0 + t * 64;
    __builtin_amdgcn_global_load_lds(GLB(kp),             LDSP(klb),        16, 0, 0);
    __builtin_amdgcn_global_load_lds(GLB(kp + 8 * HD),    LDSP(klb + 1024), 16, 0, 0);
    __builtin_amdgcn_global_load_lds(GLB(vp),             LDSP(vlb),        16, 0, 0);
    __builtin_amdgcn_global_load_lds(GLB(vp + 8 * T_SEQ), LDSP(vlb + 1024), 16, 0, 0);
  };

  auto body = [&](const u16 (*KL)[64], const u16 (*VL)[64]) {
    f32x16 s2[2] = {};
    __builtin_amdgcn_s_setprio(1);
#pragma unroll
    for (int s = 0; s < 4; s++)
#pragma unroll
      for (int kt2 = 0; kt2 < 2; kt2++) {
        int r = kt2 * 32 + pq;
        bf16x8 kf = *reinterpret_cast<const bf16x8*>(&KL[r][(((s * 2 + hi) ^ pq7) * 8)]);
        s2[kt2] = __builtin_amdgcn_mfma_f32_32x32x16_bf16(kf, qf[s], s2[kt2], 0, 0, 0);
      }

#pragma unroll
    for (int s = 0; s < 4; s++) {
      const int kt2 = s >> 1;
      const int g0 = (2 * s) & 3;
      float e0 = __builtin_amdgcn_exp2f(s2[kt2][4 * g0 + 0]);
      float e1 = __builtin_amdgcn_exp2f(s2[kt2][4 * g0 + 1]);
      float e2 = __builtin_amdgcn_exp2f(s2[kt2][4 * g0 + 2]);
      float e3 = __builtin_amdgcn_exp2f(s2[kt2][4 * g0 + 3]);
      float e4 = __builtin_amdgcn_exp2f(s2[kt2][4 * g0 + 4]);
      float e5 = __builtin_amdgcn_exp2f(s2[kt2][4 * g0 + 5]);
      float e6 = __builtin_amdgcn_exp2f(s2[kt2][4 * g0 + 6]);
      float e7 = __builtin_amdgcn_exp2f(s2[kt2][4 * g0 + 7]);
      lp += ((e0 + e1) + (e2 + e3)) + ((e4 + e5) + (e6 + e7));
      u32 w0 = __builtin_amdgcn_perm(fbits(e1), fbits(e0), 0x07060302u);
      u32 w1 = __builtin_amdgcn_perm(fbits(e3), fbits(e2), 0x07060302u);
      u32 w2 = __builtin_amdgcn_perm(fbits(e5), fbits(e4), 0x07060302u);
      u32 w3 = __builtin_amdgcn_perm(fbits(e7), fbits(e6), 0x07060302u);
      union { u32 w[4]; bf16x8 v; } pu;
      pu.w[0] = w0; pu.w[1] = w1; pu.w[2] = w2; pu.w[3] = w3;
      bf16x8 pf = pu.v;
#pragma unroll
      for (int dt = 0; dt < 2; dt++) {
        int r = dt * 32 + q32;
        bf16x8 vf = *reinterpret_cast<const bf16x8*>(&VL[r][(((s * 2 + hi) ^ (r & 7)) * 8)]);
        o2[dt] = __builtin_amdgcn_mfma_f32_32x32x16_bf16(vf, pf, o2[dt], 0, 0, 0);
      }
    }
    __builtin_amdgcn_s_setprio(0);
  };

  issue_dma(0, Kl[0], Vl[0]);
  issue_dma(1, Kl[1], Vl[1]);
  issue_dma(2, Kl[2], Vl[2]);
  u16 (*cK)[64] = Kl[0]; u16 (*cV)[64] = Vl[0];
  u16 (*nK)[64] = Kl[1]; u16 (*nV)[64] = Vl[1];
  u16 (*mK)[64] = Kl[2]; u16 (*mV)[64] = Vl[2];

  for (int t = 0; t < 29; t++) {     // re-stage t+3 (max 31)
    VMCNT(8);
    __builtin_amdgcn_s_barrier();
    body(cK, cV);
    LGKM0();
    __builtin_amdgcn_s_barrier();
    issue_dma(t + 3, cK, cV);
    u16 (*tp)[64];
    tp = cK; cK = nK; nK = mK; mK = tp;
    tp = cV; cV = nV; nV = mV; mV = tp;
  }
  VMCNT(8); __builtin_amdgcn_s_barrier(); body(cK, cV);   // t=29
  VMCNT(4); __builtin_amdgcn_s_barrier(); body(nK, nV);   // t=30
  VMCNT(0); __builtin_amdgcn_s_barrier(); body(mK, mV);   // t=31

  lp += __shfl_xor(lp, 32, 64);
  const float inv = 1.0f / lp;

  const size_t ybase = ((size_t)b * T_SEQ + qrow) * D_EMB + h * 64;
#pragma unroll
  for (int dt = 0; dt < 2; dt++)
#pragma unroll
    for (int g = 0; g < 4; g++) {
      u16 b0 = f2bf(o2[dt][4 * g + 0] * inv), b1 = f2bf(o2[dt][4 * g + 1] * inv);
      u16 b2 = f2bf(o2[dt][4 * g + 2] * inv), b3 = f2bf(o2[dt][4 * g + 3] * inv);
      u32 dw0 = (u32)b0 | ((u32)b1 << 16);
      u32 dw1 = (u32)b2 | ((u32)b3 << 16);
      *reinterpret_cast<uint2*>(&y[ybase + dt * 32 + 8 * g + 4 * hi]) = make_uint2(dw0, dw1);
    }
}

// ---------------- output projection: 64x128 tile, BK=32, depth-3 + XCD swizzle (R6-exact) ---
__global__ __launch_bounds__(256) void oproj_kernel(
    const u16* __restrict__ yw, const u16* __restrict__ Wot, float* __restrict__ out) {
  __shared__ u16 Al[3][64 * 32], Bl[3][128 * 32];
  const int tid = threadIdx.x;
  const int bid0 = blockIdx.y * 8 + blockIdx.x;          // 512 blocks
  const int wgid = (bid0 & 7) * 64 + (bid0 >> 3);
  const int nb = wgid & 7, mb = wgid >> 3;
  const int wave = tid >> 6, lane = tid & 63;
  const int ln15 = lane & 15, quad = lane >> 4;
  const int wm = wave & 1, wn = wave >> 1;

  const int srow = lane >> 2, sch = lane & 3;
  const int gch = sch ^ ((srow >> 1) & 3);
  const u16* gA = yw  + (size_t)(mb * 64 + wave * 16 + srow) * D_EMB + gch * 8;
  const u16* gB = Wot + (size_t)(nb * 128 + wave * 32 + srow) * D_EMB + gch * 8;

  auto stage = [&](int kb, u16* AL, u16* BL) {
    char* lA = (char*)AL + wave * 1024;
    char* lB = (char*)BL + wave * 2048;
    __builtin_amdgcn_global_load_lds(GLB(gA + kb), LDSP(lA), 16, 0, 0);
#pragma unroll
    for (int it = 0; it < 2; it++)
      __builtin_amdgcn_global_load_lds(GLB(gB + (size_t)it * 16 * D_EMB + kb), LDSP(lB + it * 1024), 16, 0, 0);
  };

  f32x4 acc[2][4] = {};
  bf16x8 af[2], bfr[4];

  auto ldfrag = [&](const u16* AL, const u16* BL) {
#pragma unroll
    for (int mt = 0; mt < 2; mt++) {
      int r = wm * 32 + mt * 16 + ln15;
      af[mt] = *reinterpret_cast<const bf16x8*>(&AL[r * 32 + ((quad ^ ((r >> 1) & 3)) * 8)]);
    }
#pragma unroll
    for (int nt = 0; nt < 4; nt++) {
      int r = wn * 64 + nt * 16 + ln15;
      bfr[nt] = *reinterpret_cast<const bf16x8*>(&BL[r * 32 + ((quad ^ ((r >> 1) & 3)) * 8)]);
    }
  };
  auto domfma = [&]() {
    __builtin_amdgcn_s_setprio(1);
#pragma unroll
    for (int mt = 0; mt < 2; mt++)
#pragma unroll
      for (int nt = 0; nt < 4; nt++)
        acc[mt][nt] = __builtin_amdgcn_mfma_f32_16x16x32_bf16(af[mt], bfr[nt], acc[mt][nt], 0, 0, 0);
    __builtin_amdgcn_s_setprio(0);
  };

  stage(0,  Al[0], Bl[0]);
  stage(32, Al[1], Bl[1]);
  stage(64, Al[2], Bl[2]);
  u16 *cA = Al[0], *cB = Bl[0], *nA = Al[1], *nB = Bl[1], *mA = Al[2], *mB = Bl[2];

  for (int kb = 0; kb < 928; kb += 32) {
    VMCNT(6);
    __builtin_amdgcn_s_barrier();
    ldfrag(cA, cB);
    LGKM0();
    __builtin_amdgcn_s_barrier();
    stage(kb + 96, cA, cB);
    domfma();
    u16* t;
    t = cA; cA = nA; nA = mA; mA = t;
    t = cB; cB = nB; nB = mB; mB = t;
  }
  VMCNT(6); __builtin_amdgcn_s_barrier(); ldfrag(cA, cB); domfma();   // kb=928
  VMCNT(3); __builtin_amdgcn_s_barrier(); ldfrag(nA, nB); domfma();   // kb=960
  VMCNT(0); __builtin_amdgcn_s_barrier(); ldfrag(mA, mB); domfma();   // kb=992

#pragma unroll
  for (int mt = 0; mt < 2; mt++)
#pragma unroll
    for (int nt = 0; nt < 4; nt++)
#pragma unroll
      for (int i = 0; i < 4; i++) {
        int rr = mb * 64 + wm * 32 + mt * 16 + quad * 4 + i;
        int c  = nb * 128 + wn * 64 + nt * 16 + ln15;
        out[(size_t)rr * D_EMB + c] = acc[mt][nt][i];
      }
}

extern "C" void kernel_launch(void* const* d_in, const int* in_sizes, int n_in,
                              void* d_out, int out_size, void* d_ws, size_t ws_size,
                              hipStream_t stream) {
  const float* x    = (const float*)d_in[0];
  const float* e    = (const float*)d_in[1];
  const float* W_en = (const float*)d_in[2];
  const float* W_q  = (const float*)d_in[3];
  const float* W_o  = (const float*)d_in[4];
  float* out = (float*)d_out;

  char* w = (char*)d_ws;
  u16* xb   = (u16*)(w);
  u16* eb   = (u16*)(w + (8u  << 20));
  u16* Wqt  = (u16*)(w + (16u << 20));
  u16* Went = (u16*)(w + (18u << 20));
  u16* Wot  = (u16*)(w + (22u << 20));
  u16* qw   = (u16*)(w + (24u << 20));
  u16* kw   = (u16*)(w + (32u << 20));
  u16* vT   = (u16*)(w + (40u << 20));
  u16* yw   = (u16*)(w + (48u << 20));

  prep_kernel<<<12288, 256, 0, stream>>>(x, e, W_q, W_en, W_o, xb, eb, Wqt, Went, Wot);
  proj_kernel<<<dim3(24, 32), 256, 0, stream>>>(xb, eb, Wqt, Went, qw, kw, vT);
  attn_kernel<<<512, 256, 0, stream>>>(qw, kw, vT, yw);
  oproj_kernel<<<dim3(8, 64), 256, 0, stream>>>(yw, Wot, out);
}